// Round 1
// baseline (18328.276 us; speedup 1.0000x reference)
//
#include <hip/hip_runtime.h>
#include <math.h>

#define A_NUM 9
#define NCLS 80
#define IMG_KEY 3916800
#define IMG_REG 195840
#define CAP 65536
#define HBINS 4096

__constant__ int   c_W[4]       = {64, 32, 16, 8};
__constant__ int   c_stride[4]  = {8, 16, 32, 64};
__constant__ float c_sizes[4][3]= {{32.f,40.f,50.f},{64.f,80.f,101.f},{128.f,161.f,203.f},{256.f,322.f,406.f}};
__constant__ int   c_keyOff[4]  = {0, 2949120, 3686400, 3870720};
__constant__ int   c_keyCnt[4]  = {2949120, 737280, 184320, 46080};
__constant__ int   c_regOff[4]  = {0, 147456, 184320, 193536};

// ---------------------------------------------------------------------------
// Direct 3x3 SAME conv, fp32. Block: 64 out-channels x 64 pixels (8x8 tile).
// Thread: 4 co x (2x2) px register tile. ci staged in chunks of 8 through LDS.
// mode 0: NCHW out. mode 1: cls epilogue (sigmoid->key). mode 2: reg epilogue.
// ---------------------------------------------------------------------------
__global__ __launch_bounds__(256) void conv3x3(
    const float* __restrict__ in, const float* __restrict__ w,
    const float* __restrict__ bias, float* __restrict__ outN,
    unsigned* __restrict__ keyOut, float* __restrict__ regOut,
    int C_out, int H, int W, int relu, int mode, int lvl)
{
    const int tid = threadIdx.x;
    const int img = blockIdx.z;
    const int coBase = blockIdx.y * 64;
    const int tilesX = W >> 3;
    const int tileX = (blockIdx.x % tilesX) * 8;
    const int tileY = (blockIdx.x / tilesX) * 8;
    const int cog = tid >> 4;
    const int pg  = tid & 15;
    const int px0 = (pg & 3) * 2;
    const int py0 = (pg >> 2) * 2;

    __shared__ float sIn[800];    // [ci][iy*10+ix], 8x10x10
    __shared__ float sW[4672];    // [coL*73 + ci*9 + k], pad 72->73 breaks 4-way bank conflict

    float acc[4][4] = {};
    const float* inImg = in + (size_t)img * 256 * H * W;

    for (int cc = 0; cc < 256; cc += 8) {
        for (int t = tid; t < 800; t += 256) {
            int ci = t / 100, rem = t % 100;
            int iy = rem / 10, ix = rem % 10;
            int gy = tileY + iy - 1, gx = tileX + ix - 1;
            float v = 0.f;
            if (gy >= 0 && gy < H && gx >= 0 && gx < W)
                v = inImg[((cc + ci) * H + gy) * W + gx];
            sIn[t] = v;
        }
        for (int t = tid; t < 4608; t += 256) {
            int coL = t / 72, rem = t % 72;
            int coG = coBase + coL;
            float v = (coG < C_out) ? w[((size_t)coG * 256 + cc + rem / 9) * 9 + (rem % 9)] : 0.f;
            sW[coL * 73 + rem] = v;
        }
        __syncthreads();
        #pragma unroll
        for (int ci = 0; ci < 8; ++ci) {
            float xin[4][4];
            #pragma unroll
            for (int iy = 0; iy < 4; ++iy)
                #pragma unroll
                for (int ix = 0; ix < 4; ++ix)
                    xin[iy][ix] = sIn[ci * 100 + (py0 + iy) * 10 + (px0 + ix)];
            #pragma unroll
            for (int r = 0; r < 4; ++r) {
                float wr[9];
                #pragma unroll
                for (int k = 0; k < 9; ++k) wr[k] = sW[(cog * 4 + r) * 73 + ci * 9 + k];
                #pragma unroll
                for (int py = 0; py < 2; ++py)
                    #pragma unroll
                    for (int px = 0; px < 2; ++px)
                        #pragma unroll
                        for (int ky = 0; ky < 3; ++ky)
                            #pragma unroll
                            for (int kx = 0; kx < 3; ++kx)
                                acc[r][py * 2 + px] = fmaf(xin[py + ky][px + kx], wr[ky * 3 + kx], acc[r][py * 2 + px]);
            }
        }
        __syncthreads();
    }

    for (int r = 0; r < 4; ++r) {
        int coG = coBase + cog * 4 + r;
        if (coG >= C_out) continue;
        float b = bias[coG];
        for (int py = 0; py < 2; ++py) {
            for (int px = 0; px < 2; ++px) {
                int y = tileY + py0 + py, x = tileX + px0 + px;
                float v = acc[r][py * 2 + px] + b;
                if (relu) v = fmaxf(v, 0.f);
                int p = y * W + x;
                if (mode == 0) {
                    outN[(((size_t)img * 256 + coG) * H + y) * W + x] = v;
                } else if (mode == 1) {
                    float s = 1.0f / (1.0f + expf(-v));
                    unsigned key = (s > 0.05f) ? __float_as_uint(s) : 0u;
                    int a = coG / NCLS, cch = coG - a * NCLS;
                    keyOut[(size_t)img * IMG_KEY + c_keyOff[lvl] + (size_t)(p * A_NUM + a) * NCLS + cch] = key;
                } else {
                    int a = coG >> 2, jj = coG & 3;
                    regOut[(size_t)img * IMG_REG + c_regOff[lvl] + (size_t)(p * A_NUM + a) * 4 + jj] = v;
                }
            }
        }
    }
}

// ---------------------------------------------------------------------------
__global__ void hist_k(const unsigned* __restrict__ keys, unsigned* __restrict__ hist)
{
    int il = blockIdx.y, img = il >> 2, lvl = il & 3;
    int n = c_keyCnt[lvl];
    int chunk = blockIdx.x * 16384;
    __shared__ unsigned h[HBINS];
    for (int t = threadIdx.x; t < HBINS; t += 256) h[t] = 0;
    __syncthreads();
    if (chunk < n) {
        const unsigned* k = keys + (size_t)img * IMG_KEY + c_keyOff[lvl];
        int end = min(chunk + 16384, n);
        for (int t = chunk + (int)threadIdx.x; t < end; t += 256)
            atomicAdd(&h[k[t] >> 20], 1u);
    }
    __syncthreads();
    unsigned* gh = hist + (size_t)il * HBINS;
    for (int t = threadIdx.x; t < HBINS; t += 256)
        if (h[t]) atomicAdd(&gh[t], h[t]);
}

__global__ void thresh_k(const unsigned* __restrict__ hist, unsigned* __restrict__ tbin)
{
    if (threadIdx.x != 0) return;
    const unsigned* h = hist + (size_t)blockIdx.x * HBINS;
    unsigned total = 0; unsigned sel = 0;
    for (int b = HBINS - 1; b >= 1; --b) {
        total += h[b];
        if (total >= 100) { sel = (unsigned)b; break; }
    }
    tbin[blockIdx.x] = sel;
}

__global__ void compact_k(const unsigned* __restrict__ keys, const unsigned* __restrict__ tbin,
                          unsigned* __restrict__ cnt, uint2* __restrict__ comp)
{
    int il = blockIdx.y, img = il >> 2, lvl = il & 3;
    int n = c_keyCnt[lvl];
    int chunk = blockIdx.x * 16384;
    if (chunk >= n) return;
    const unsigned* k = keys + (size_t)img * IMG_KEY + c_keyOff[lvl];
    unsigned thr = tbin[il] << 20;
    uint2* c = comp + (size_t)il * CAP;
    int end = min(chunk + 16384, n);
    for (int t = chunk + (int)threadIdx.x; t < end; t += 256) {
        unsigned key = k[t];
        if (key != 0u && key >= thr) {
            unsigned pos = atomicAdd(&cnt[il], 1u);
            if (pos < CAP) c[pos] = make_uint2(key, (unsigned)t);
        }
    }
}

// top-100 by (key desc, idx asc) — matches lax.top_k stable tie-break.
__global__ __launch_bounds__(256) void select_k(const unsigned* __restrict__ cnt,
                                                uint2* __restrict__ comp, uint2* __restrict__ topk)
{
    int il = blockIdx.x;
    int n = (int)min(cnt[il], (unsigned)CAP);
    uint2* c = comp + (size_t)il * CAP;
    __shared__ unsigned long long sC[256];
    __shared__ int sP[256];
    int tid = threadIdx.x;
    for (int j = 0; j < 100; ++j) {
        unsigned long long best = 0ull; int bp = -1;
        for (int t = tid; t < n; t += 256) {
            unsigned key = c[t].x;
            if (key) {
                unsigned long long cm = ((unsigned long long)key << 32) |
                                        (unsigned long long)(0xFFFFFFFFu - c[t].y);
                if (cm > best) { best = cm; bp = t; }
            }
        }
        sC[tid] = best; sP[tid] = bp;
        __syncthreads();
        for (int s = 128; s > 0; s >>= 1) {
            if (tid < s && sC[tid + s] > sC[tid]) { sC[tid] = sC[tid + s]; sP[tid] = sP[tid + s]; }
            __syncthreads();
        }
        if (tid == 0) {
            unsigned long long b = sC[0];
            if (b) {
                topk[il * 100 + j] = make_uint2((unsigned)(b >> 32), 0xFFFFFFFFu - (unsigned)(b & 0xFFFFFFFFu));
                c[sP[0]].x = 0u;
            } else {
                topk[il * 100 + j] = make_uint2(0u, 0u);
            }
        }
        __syncthreads();
    }
}

// anchors + box decode + clip, per selected entry
__global__ void decode_k(const uint2* __restrict__ topk, const float* __restrict__ regb,
                         float* __restrict__ cboxes, float* __restrict__ cscores,
                         int* __restrict__ clabels, const int* __restrict__ ph, const int* __restrict__ pw)
{
    int il = blockIdx.x, img = il >> 2, lvl = il & 3;
    int j = threadIdx.x;
    if (j >= 100) return;
    float imgW = (float)pw[0], imgH = (float)ph[0];
    uint2 tk = topk[il * 100 + j];
    int outP = img * 400 + lvl * 100 + j;
    if (tk.x == 0u) {
        cboxes[outP * 4 + 0] = 0.f; cboxes[outP * 4 + 1] = 0.f;
        cboxes[outP * 4 + 2] = 0.f; cboxes[outP * 4 + 3] = 0.f;
        cscores[outP] = -1.0f; clabels[outP] = -1;
        return;
    }
    float score = __uint_as_float(tk.x);
    unsigned idx = tk.y;
    int aidx = (int)(idx / NCLS);
    int lbl  = (int)(idx - (unsigned)aidx * NCLS);
    int a = aidx % A_NUM, p = aidx / A_NUM;
    int W = c_W[lvl];
    int y = p / W, x = p - y * W;
    int r = a / 3, si = a - r * 3;
    float ratio = (r == 0) ? 0.5f : ((r == 1) ? 1.0f : 2.0f);
    float size = c_sizes[lvl][si];
    float hr = sqrtf(ratio);
    float wr = 1.0f / hr;
    float wsz = wr * size, hsz = hr * size;
    float bw = rintf(wsz * 0.5f), bh = rintf(hsz * 0.5f);
    float sx = (float)(x * c_stride[lvl]), sy = (float)(y * c_stride[lvl]);
    float ax1 = fminf(fmaxf(sx - bw, 0.f), imgW);
    float ay1 = fminf(fmaxf(sy - bh, 0.f), imgH);
    float ax2 = fminf(fmaxf(sx + bw, 0.f), imgW);
    float ay2 = fminf(fmaxf(sy + bh, 0.f), imgH);
    float aw = ax2 - ax1, ah = ay2 - ay1;
    float cx = ax1 + 0.5f * aw, cy = ay1 + 0.5f * ah;
    const float* rel = regb + (size_t)img * IMG_REG + c_regOff[lvl] + (size_t)aidx * 4;
    float dx = rel[0], dy = rel[1];
    float dw = fminf(rel[2], 4.135166556742356f);
    float dh = fminf(rel[3], 4.135166556742356f);
    float pcx = dx * aw + cx, pcy = dy * ah + cy;
    float pwd = expf(dw) * aw, phd = expf(dh) * ah;
    float x1 = pcx - 0.5f * pwd, y1 = pcy - 0.5f * phd;
    float x2 = pcx + 0.5f * pwd, y2 = pcy + 0.5f * phd;
    cboxes[outP * 4 + 0] = fminf(fmaxf(x1, 0.f), imgW);
    cboxes[outP * 4 + 1] = fminf(fmaxf(y1, 0.f), imgH);
    cboxes[outP * 4 + 2] = fminf(fmaxf(x2, 0.f), imgW);
    cboxes[outP * 4 + 3] = fminf(fmaxf(y2, 0.f), imgH);
    cscores[outP] = score;
    clabels[outP] = lbl;
}

// per-image: stable-descending sort of 400, greedy NMS, final top-100 emit
__global__ __launch_bounds__(512) void nms_k(const float* __restrict__ cboxes,
                                             const float* __restrict__ cscores,
                                             const int* __restrict__ clabels,
                                             const int* __restrict__ ph, const int* __restrict__ pw,
                                             float* __restrict__ out)
{
    int img = blockIdx.x, tid = threadIdx.x;
    __shared__ float sSc[512];
    __shared__ int   sPos[512];
    __shared__ float bx1[400], by1[400], bx2[400], by2[400], sAr[400];
    __shared__ int   sKeep[400], sLbl[400];
    float imgH = (float)ph[0], imgW = (float)pw[0];
    float offm = fmaxf(imgH, imgW) + 1.0f;

    sSc[tid] = (tid < 400) ? cscores[img * 400 + tid] : -3.0f;
    sPos[tid] = tid;
    __syncthreads();

    // bitonic, descending by (score, then pos ascending) == jnp stable argsort(-scores)
    for (int k = 2; k <= 512; k <<= 1) {
        for (int jj = k >> 1; jj > 0; jj >>= 1) {
            int ixj = tid ^ jj;
            if (ixj > tid) {
                float s1 = sSc[tid], s2 = sSc[ixj];
                int p1 = sPos[tid], p2 = sPos[ixj];
                bool bef = (s1 > s2) || (s1 == s2 && p1 < p2);
                bool sw = ((tid & k) == 0) ? (!bef) : bef;
                if (sw) { sSc[tid] = s2; sSc[ixj] = s1; sPos[tid] = p2; sPos[ixj] = p1; }
            }
            __syncthreads();
        }
    }

    if (tid < 400) {
        int p = sPos[tid];
        int lbl = clabels[img * 400 + p];
        float ofs = (float)lbl * offm;
        float x1 = cboxes[(img * 400 + p) * 4 + 0] + ofs;
        float y1 = cboxes[(img * 400 + p) * 4 + 1] + ofs;
        float x2 = cboxes[(img * 400 + p) * 4 + 2] + ofs;
        float y2 = cboxes[(img * 400 + p) * 4 + 3] + ofs;
        bx1[tid] = x1; by1[tid] = y1; bx2[tid] = x2; by2[tid] = y2;
        sAr[tid] = (x2 - x1) * (y2 - y1);
        sLbl[tid] = lbl;
        sKeep[tid] = (sSc[tid] > 0.05f) ? 1 : 0;
    }
    __syncthreads();

    for (int i = 0; i < 400; ++i) {
        int ki = sKeep[i];
        if (ki) {
            for (int j2 = i + 1 + tid; j2 < 400; j2 += 512) {
                float ltx = fmaxf(bx1[i], bx1[j2]), lty = fmaxf(by1[i], by1[j2]);
                float rbx = fminf(bx2[i], bx2[j2]), rby = fminf(by2[i], by2[j2]);
                float ww = fmaxf(rbx - ltx, 0.f), hh = fmaxf(rby - lty, 0.f);
                float inter = ww * hh;
                float iou = inter / (((sAr[i] + sAr[j2]) - inter) + 1e-9f);
                if (iou > 0.5f) sKeep[j2] = 0;
            }
        }
        __syncthreads();
    }

    if (tid == 0) {
        int rank = 0;
        for (int i = 0; i < 400 && rank < 100; ++i) {
            if (sKeep[i]) {
                int p = sPos[i];
                for (int kk = 0; kk < 4; ++kk)
                    out[(img * 100 + rank) * 4 + kk] = cboxes[(img * 400 + p) * 4 + kk];
                out[1600 + img * 100 + rank] = sSc[i];
                out[2000 + img * 100 + rank] = (float)sLbl[i];
                ++rank;
            }
        }
        for (; rank < 100; ++rank) {
            for (int kk = 0; kk < 4; ++kk) out[(img * 100 + rank) * 4 + kk] = 0.f;
            out[1600 + img * 100 + rank] = 0.f;
            out[2000 + img * 100 + rank] = -1.0f;
        }
    }
}

// ---------------------------------------------------------------------------
extern "C" void kernel_launch(void* const* d_in, const int* in_sizes, int n_in,
                              void* d_out, int out_size, void* d_ws, size_t ws_size,
                              hipStream_t stream)
{
    const float* f[4] = {(const float*)d_in[0], (const float*)d_in[1],
                         (const float*)d_in[2], (const float*)d_in[3]};
    const float* cls_tw = (const float*)d_in[4];
    const float* cls_tb = (const float*)d_in[5];
    const float* cls_ow = (const float*)d_in[6];
    const float* cls_ob = (const float*)d_in[7];
    const float* reg_tw = (const float*)d_in[8];
    const float* reg_tb = (const float*)d_in[9];
    const float* reg_ow = (const float*)d_in[10];
    const float* reg_ob = (const float*)d_in[11];
    const int* ph = (const int*)d_in[12];
    const int* pw = (const int*)d_in[13];
    float* out = (float*)d_out;

    char* ws = (char*)d_ws;
    size_t off = 0;
    auto alloc = [&](size_t bytes) -> void* {
        void* p = ws + off;
        off = (off + bytes + 255) & ~(size_t)255;
        return p;
    };
    float*    buf0   = (float*)alloc((size_t)4 * 256 * 64 * 64 * 4);
    float*    buf1   = (float*)alloc((size_t)4 * 256 * 64 * 64 * 4);
    unsigned* keys   = (unsigned*)alloc((size_t)4 * IMG_KEY * 4);
    float*    regb   = (float*)alloc((size_t)4 * IMG_REG * 4);
    unsigned* hist   = (unsigned*)alloc((size_t)16 * HBINS * 4);
    unsigned* cnt    = (unsigned*)alloc(16 * 4);
    unsigned* tbin   = (unsigned*)alloc(16 * 4);
    uint2*    comp   = (uint2*)alloc((size_t)16 * CAP * 8);
    uint2*    topk   = (uint2*)alloc((size_t)1600 * 8);
    float*    cboxes = (float*)alloc((size_t)4 * 400 * 4 * 4);
    float*    cscores= (float*)alloc((size_t)4 * 400 * 4);
    int*      clabels= (int*)alloc((size_t)4 * 400 * 4);

    hipMemsetAsync(hist, 0, (size_t)16 * HBINS * 4, stream);
    hipMemsetAsync(cnt, 0, 64, stream);

    for (int head = 0; head < 2; ++head) {
        const float* tw = head ? reg_tw : cls_tw;
        const float* tb = head ? reg_tb : cls_tb;
        for (int lvl = 0; lvl < 4; ++lvl) {
            int H = 64 >> lvl;
            int tiles = (H / 8) * (H / 8);
            const float* src = f[lvl];
            for (int layer = 0; layer < 4; ++layer) {
                float* dst = (layer & 1) ? buf1 : buf0;
                conv3x3<<<dim3(tiles, 4, 4), 256, 0, stream>>>(
                    src, tw + (size_t)layer * 256 * 256 * 9, tb + layer * 256,
                    dst, (unsigned*)nullptr, (float*)nullptr, 256, H, H, 1, 0, lvl);
                src = dst;
            }
            if (head == 0)
                conv3x3<<<dim3(tiles, 12, 4), 256, 0, stream>>>(
                    src, cls_ow, cls_ob, (float*)nullptr, keys, (float*)nullptr, 720, H, H, 0, 1, lvl);
            else
                conv3x3<<<dim3(tiles, 1, 4), 256, 0, stream>>>(
                    src, reg_ow, reg_ob, (float*)nullptr, (unsigned*)nullptr, regb, 36, H, H, 0, 2, lvl);
        }
    }

    hist_k<<<dim3(180, 16), 256, 0, stream>>>(keys, hist);
    thresh_k<<<16, 64, 0, stream>>>(hist, tbin);
    compact_k<<<dim3(180, 16), 256, 0, stream>>>(keys, tbin, cnt, comp);
    select_k<<<16, 256, 0, stream>>>(cnt, comp, topk);
    decode_k<<<16, 128, 0, stream>>>(topk, regb, cboxes, cscores, clabels, ph, pw);
    nms_k<<<4, 512, 0, stream>>>(cboxes, cscores, clabels, ph, pw, out);
}

// Round 2
// 6877.650 us; speedup vs baseline: 2.6649x; 2.6649x over previous
//
#include <hip/hip_runtime.h>
#include <math.h>

#define A_NUM 9
#define NCLS 80
#define IMG_KEY 3916800   // 720*5440
#define IMG_REG 195840    // 36*5440
#define CAP 32768
#define HBINS 4096
#define CONCAT_PX 5440

__constant__ int   c_W[4]       = {64, 32, 16, 8};
__constant__ int   c_stride[4]  = {8, 16, 32, 64};
__constant__ float c_sizes[4][3]= {{32.f,40.f,50.f},{64.f,80.f,101.f},{128.f,161.f,203.f},{256.f,322.f,406.f}};
__constant__ int   c_keyOff[4]  = {0, 2949120, 3686400, 3870720};
__constant__ int   c_keyCnt[4]  = {2949120, 737280, 184320, 46080};
__constant__ int   c_regOff[4]  = {0, 147456, 184320, 193536};
__constant__ int   c_lvlPx[4]   = {0, 4096, 5120, 5376};

// ---------------------------------------------------------------------------
// Fused 3x3 SAME conv, fp32, all 4 levels in one dispatch (43 tiles of 8x16 px).
// mode 0: tower layer (grid.z = head*4+img, grid.y = co-group of 64, ReLU,
//         write concat-layout buffer). layer==0 reads f[lvl] (NCHW), else bufIn.
// mode 1: fused out-convs (grid.z = img; grid.y<12 -> cls 720ch sigmoid->keys,
//         grid.y==12 -> reg 36ch -> regb).
// Thread tile: 4 co x (2 rows x 4 cols). Per ci: 288 FMA, ~28 vector DS reads.
// ---------------------------------------------------------------------------
__global__ __launch_bounds__(256) void conv_fused(
    const float* __restrict__ f0, const float* __restrict__ f1,
    const float* __restrict__ f2, const float* __restrict__ f3,
    const float* __restrict__ bufIn, float* __restrict__ bufOut,
    const float* __restrict__ wA, const float* __restrict__ bA,
    const float* __restrict__ wB, const float* __restrict__ bB,
    unsigned* __restrict__ keys, float* __restrict__ regb,
    int layer, int mode)
{
    const int tid = threadIdx.x;
    int t43 = blockIdx.x;
    int lvl, ty, tx;
    if (t43 < 32)      { lvl = 0; ty = t43 >> 2; tx = t43 & 3; }
    else if (t43 < 40) { int u = t43 - 32; lvl = 1; ty = u >> 1; tx = u & 1; }
    else if (t43 < 42) { lvl = 2; ty = t43 - 40; tx = 0; }
    else               { lvl = 3; ty = 0; tx = 0; }
    const int W = 64 >> lvl, H = W, HW = W * W;
    const int tileY = ty * 8, tileX = tx * 16;

    int img, head, coBase, C_out, epi;
    const float *wsel, *bsel;
    if (mode == 0) {
        img = blockIdx.z & 3; head = blockIdx.z >> 2;
        coBase = blockIdx.y * 64; C_out = 256; epi = 0;
        wsel = head ? wB : wA; bsel = head ? bB : bA;
    } else {
        img = blockIdx.z;
        if (blockIdx.y < 12) { head = 0; coBase = blockIdx.y * 64; C_out = 720; epi = 1; wsel = wA; bsel = bA; }
        else                 { head = 1; coBase = 0;               C_out = 36;  epi = 2; wsel = wB; bsel = bB; }
    }

    const float* srcBase; int chStride;
    if (mode == 0 && layer == 0) {
        const float* f = (lvl == 0) ? f0 : ((lvl == 1) ? f1 : ((lvl == 2) ? f2 : f3));
        srcBase = f + (size_t)img * 256 * HW; chStride = HW;
    } else {
        srcBase = bufIn + ((size_t)(head * 4 + img) * 256) * CONCAT_PX + c_lvlPx[lvl];
        chStride = CONCAT_PX;
    }
    const float* wBase = wsel + (size_t)coBase * 2304;

    const int cog4 = (tid >> 4) * 4;
    const int pg   = tid & 15;
    const int py0  = (pg >> 2) * 2;
    const int px0  = (pg & 3) * 4;

    __shared__ float sIn[1600];   // 8ci x 10 rows x 20 cols (18 valid + pad)
    __shared__ float sW[5120];    // 64co x (8ci x 10)

    // precompute staging offsets once (no div/mod in hot loop)
    int inOff[7];
    #pragma unroll
    for (int e = 0; e < 7; ++e) {
        int t = tid + e * 256;
        int off = -1;
        if (t < 1600) {
            int ci = t / 200, rem = t - ci * 200;
            int iy = rem / 20, ix = rem - iy * 20;
            int gy = tileY + iy - 1, gx = tileX + ix - 1;
            if (ix < 18 && (unsigned)gy < (unsigned)H && (unsigned)gx < (unsigned)W)
                off = ci * chStride + gy * W + gx;
        }
        inOff[e] = off;
    }
    int wOff[18], wLds[18];
    #pragma unroll
    for (int e = 0; e < 18; ++e) {
        int t = tid + e * 256;                 // t < 4608 exactly
        int coL = t / 72, rem = t - coL * 72;
        int ciL = rem / 9, kk = rem - ciL * 9;
        wLds[e] = coL * 80 + ciL * 10 + kk;
        wOff[e] = (coBase + coL < C_out) ? (coL * 2304 + ciL * 9 + kk) : -1;
    }

    float acc[4][8] = {};

    for (int cc = 0; cc < 256; cc += 8) {
        const int ccS = cc * chStride;
        #pragma unroll
        for (int e = 0; e < 7; ++e) {
            int t = tid + e * 256;
            if (t < 1600) sIn[t] = (inOff[e] >= 0) ? srcBase[ccS + inOff[e]] : 0.f;
        }
        const int cc9 = cc * 9;
        #pragma unroll
        for (int e = 0; e < 18; ++e)
            sW[wLds[e]] = (wOff[e] >= 0) ? wBase[cc9 + wOff[e]] : 0.f;
        __syncthreads();

        #pragma unroll
        for (int ci = 0; ci < 8; ++ci) {
            float xr[4][6];
            #pragma unroll
            for (int iy = 0; iy < 4; ++iy) {
                const float4 a = *reinterpret_cast<const float4*>(&sIn[ci * 200 + (py0 + iy) * 20 + px0]);
                const float2 b = *reinterpret_cast<const float2*>(&sIn[ci * 200 + (py0 + iy) * 20 + px0 + 4]);
                xr[iy][0] = a.x; xr[iy][1] = a.y; xr[iy][2] = a.z; xr[iy][3] = a.w;
                xr[iy][4] = b.x; xr[iy][5] = b.y;
            }
            #pragma unroll
            for (int r = 0; r < 4; ++r) {
                const int wb = (cog4 + r) * 80 + ci * 10;
                float wr[9];
                const float2 w0 = *reinterpret_cast<const float2*>(&sW[wb]);
                const float2 w1 = *reinterpret_cast<const float2*>(&sW[wb + 2]);
                const float2 w2 = *reinterpret_cast<const float2*>(&sW[wb + 4]);
                const float2 w3 = *reinterpret_cast<const float2*>(&sW[wb + 6]);
                wr[0] = w0.x; wr[1] = w0.y; wr[2] = w1.x; wr[3] = w1.y;
                wr[4] = w2.x; wr[5] = w2.y; wr[6] = w3.x; wr[7] = w3.y; wr[8] = sW[wb + 8];
                #pragma unroll
                for (int py = 0; py < 2; ++py)
                    #pragma unroll
                    for (int px = 0; px < 4; ++px) {
                        float s = acc[r][py * 4 + px];
                        #pragma unroll
                        for (int ky = 0; ky < 3; ++ky)
                            #pragma unroll
                            for (int kx = 0; kx < 3; ++kx)
                                s = fmaf(xr[py + ky][px + kx], wr[ky * 3 + kx], s);
                        acc[r][py * 4 + px] = s;
                    }
            }
        }
        __syncthreads();
    }

    if (px0 >= W) return;   // lvl3 right-half threads
    #pragma unroll
    for (int r = 0; r < 4; ++r) {
        int coG = coBase + cog4 + r;
        if (coG >= C_out) continue;
        float b = bsel[coG];
        for (int py = 0; py < 2; ++py) {
            int y = tileY + py0 + py;
            float v0 = acc[r][py * 4 + 0] + b;
            float v1 = acc[r][py * 4 + 1] + b;
            float v2 = acc[r][py * 4 + 2] + b;
            float v3 = acc[r][py * 4 + 3] + b;
            if (epi == 0) {
                v0 = fmaxf(v0, 0.f); v1 = fmaxf(v1, 0.f); v2 = fmaxf(v2, 0.f); v3 = fmaxf(v3, 0.f);
                float* o = bufOut + ((size_t)(head * 4 + img) * 256 + coG) * CONCAT_PX
                                  + c_lvlPx[lvl] + y * W + tileX + px0;
                *reinterpret_cast<float4*>(o) = make_float4(v0, v1, v2, v3);
            } else if (epi == 1) {
                float s0 = 1.0f / (1.0f + expf(-v0));
                float s1 = 1.0f / (1.0f + expf(-v1));
                float s2 = 1.0f / (1.0f + expf(-v2));
                float s3 = 1.0f / (1.0f + expf(-v3));
                unsigned k0 = (s0 > 0.05f) ? __float_as_uint(s0) : 0u;
                unsigned k1 = (s1 > 0.05f) ? __float_as_uint(s1) : 0u;
                unsigned k2 = (s2 > 0.05f) ? __float_as_uint(s2) : 0u;
                unsigned k3 = (s3 > 0.05f) ? __float_as_uint(s3) : 0u;
                unsigned* o = keys + (size_t)img * IMG_KEY + c_keyOff[lvl]
                                   + (size_t)coG * HW + y * W + tileX + px0;
                *reinterpret_cast<uint4*>(o) = make_uint4(k0, k1, k2, k3);
            } else {
                int a = coG >> 2, jj = coG & 3;
                int pBase = y * W + tileX + px0;
                #pragma unroll
                for (int px = 0; px < 4; ++px) {
                    float v = acc[r][py * 4 + px] + b;
                    regb[(size_t)img * IMG_REG + c_regOff[lvl] + (size_t)((pBase + px) * A_NUM + a) * 4 + jj] = v;
                }
            }
        }
    }
}

// ---------------------------------------------------------------------------
__global__ void hist_k(const unsigned* __restrict__ keys, unsigned* __restrict__ hist)
{
    int il = blockIdx.y, img = il >> 2, lvl = il & 3;
    int n = c_keyCnt[lvl];
    int chunk = blockIdx.x * 16384;
    __shared__ unsigned h[HBINS];
    for (int t = threadIdx.x; t < HBINS; t += 256) h[t] = 0;
    __syncthreads();
    if (chunk < n) {
        const unsigned* k = keys + (size_t)img * IMG_KEY + c_keyOff[lvl];
        int end = min(chunk + 16384, n);
        for (int t = chunk + (int)threadIdx.x; t < end; t += 256) {
            unsigned kk = k[t];
            if (kk) atomicAdd(&h[kk >> 20], 1u);
        }
    }
    __syncthreads();
    unsigned* gh = hist + (size_t)il * HBINS;
    for (int t = threadIdx.x; t < HBINS; t += 256)
        if (h[t]) atomicAdd(&gh[t], h[t]);
}

__global__ void thresh_k(const unsigned* __restrict__ hist, unsigned* __restrict__ tbin)
{
    __shared__ unsigned hb[HBINS];
    __shared__ unsigned cs[256];
    const unsigned* h = hist + (size_t)blockIdx.x * HBINS;
    int tid = threadIdx.x;
    for (int i = tid; i < HBINS; i += 256) hb[i] = h[i];
    __syncthreads();
    unsigned s = 0; int base = tid * 16;
    for (int q = 0; q < 16; ++q) { int b = base + q; if (b >= 1) s += hb[b]; }
    cs[tid] = s;
    __syncthreads();
    if (tid == 0) {
        unsigned total = 0, sel = 0;
        for (int c = 255; c >= 0; --c) {
            if (total + cs[c] >= 100u) {
                int lo = (c == 0) ? 1 : c * 16;
                for (int b = c * 16 + 15; b >= lo; --b) {
                    total += hb[b];
                    if (total >= 100u) { sel = (unsigned)b; break; }
                }
                break;
            }
            total += cs[c];
        }
        tbin[blockIdx.x] = sel;
    }
}

__global__ void compact_k(const unsigned* __restrict__ keys, const unsigned* __restrict__ tbin,
                          unsigned* __restrict__ cnt, uint2* __restrict__ comp)
{
    int il = blockIdx.y, img = il >> 2, lvl = il & 3;
    int n = c_keyCnt[lvl];
    int chunk = blockIdx.x * 16384;
    if (chunk >= n) return;
    const unsigned* k = keys + (size_t)img * IMG_KEY + c_keyOff[lvl];
    unsigned thr = tbin[il] << 20;
    uint2* c = comp + (size_t)il * CAP;
    int shift = 12 - 2 * lvl;
    int hwm = (1 << shift) - 1;
    int end = min(chunk + 16384, n);
    for (int t = chunk + (int)threadIdx.x; t < end; t += 256) {
        unsigned key = k[t];
        if (key != 0u && key >= thr) {
            int co = t >> shift, p = t & hwm;
            int a = co / NCLS, cls = co - a * NCLS;
            unsigned idx = (unsigned)((p * A_NUM + a) * NCLS + cls);   // reference flat index
            unsigned pos = atomicAdd(&cnt[il], 1u);
            if (pos < CAP) c[pos] = make_uint2(key, idx);
        }
    }
}

// ---------------------------------------------------------------------------
__device__ inline void bitonic2048_desc(unsigned long long* s, int tid)
{
    for (int k = 2; k <= 2048; k <<= 1)
        for (int j = k >> 1; j > 0; j >>= 1) {
            __syncthreads();
            for (int i = tid; i < 2048; i += 256) {
                int ixj = i ^ j;
                if (ixj > i) {
                    unsigned long long a = s[i], b = s[ixj];
                    bool front = ((i & k) == 0);
                    if (front ? (a < b) : (a > b)) { s[i] = b; s[ixj] = a; }
                }
            }
        }
    __syncthreads();
}

// per-2048-chunk top-100 (sorted desc by composite (score, ~idx))
__global__ __launch_bounds__(256) void partial_topk(const unsigned* __restrict__ cnt,
                                                    const uint2* __restrict__ comp,
                                                    unsigned long long* __restrict__ part)
{
    int il = blockIdx.y, ch = blockIdx.x, tid = threadIdx.x;
    int n = (int)min(cnt[il], (unsigned)CAP);
    int start = ch * 2048;
    __shared__ unsigned long long s[2048];
    const uint2* c = comp + (size_t)il * CAP;
    for (int i = tid; i < 2048; i += 256) {
        int g = start + i;
        unsigned long long v = 0ull;
        if (g < n) {
            uint2 e = c[g];
            v = ((unsigned long long)e.x << 32) | (unsigned long long)(~e.y);
        }
        s[i] = v;
    }
    bitonic2048_desc(s, tid);
    if (tid < 100) part[(size_t)(il * 16 + ch) * 100 + tid] = s[tid];
}

__global__ __launch_bounds__(256) void merge_topk(const unsigned long long* __restrict__ part,
                                                  uint2* __restrict__ topk)
{
    int il = blockIdx.x, tid = threadIdx.x;
    __shared__ unsigned long long s[2048];
    for (int i = tid; i < 2048; i += 256)
        s[i] = (i < 1600) ? part[(size_t)il * 1600 + i] : 0ull;
    bitonic2048_desc(s, tid);
    if (tid < 100) {
        unsigned long long v = s[tid];
        topk[il * 100 + tid] = make_uint2((unsigned)(v >> 32), ~(unsigned)(v & 0xFFFFFFFFull));
    }
}

// ---------------------------------------------------------------------------
__global__ void decode_k(const uint2* __restrict__ topk, const float* __restrict__ regb,
                         float* __restrict__ cboxes, float* __restrict__ cscores,
                         int* __restrict__ clabels, const int* __restrict__ ph, const int* __restrict__ pw)
{
    int il = blockIdx.x, img = il >> 2, lvl = il & 3;
    int j = threadIdx.x;
    if (j >= 100) return;
    float imgW = (float)pw[0], imgH = (float)ph[0];
    uint2 tk = topk[il * 100 + j];
    int outP = img * 400 + lvl * 100 + j;
    if (tk.x == 0u) {
        cboxes[outP * 4 + 0] = 0.f; cboxes[outP * 4 + 1] = 0.f;
        cboxes[outP * 4 + 2] = 0.f; cboxes[outP * 4 + 3] = 0.f;
        cscores[outP] = -1.0f; clabels[outP] = -1;
        return;
    }
    float score = __uint_as_float(tk.x);
    unsigned idx = tk.y;
    int aidx = (int)(idx / NCLS);
    int lbl  = (int)(idx - (unsigned)aidx * NCLS);
    int a = aidx % A_NUM, p = aidx / A_NUM;
    int W = c_W[lvl];
    int y = p / W, x = p - y * W;
    int r = a / 3, si = a - r * 3;
    float ratio = (r == 0) ? 0.5f : ((r == 1) ? 1.0f : 2.0f);
    float size = c_sizes[lvl][si];
    float hr = sqrtf(ratio);
    float wr = 1.0f / hr;
    float wsz = wr * size, hsz = hr * size;
    float bw = rintf(wsz * 0.5f), bh = rintf(hsz * 0.5f);
    float sx = (float)(x * c_stride[lvl]), sy = (float)(y * c_stride[lvl]);
    float ax1 = fminf(fmaxf(sx - bw, 0.f), imgW);
    float ay1 = fminf(fmaxf(sy - bh, 0.f), imgH);
    float ax2 = fminf(fmaxf(sx + bw, 0.f), imgW);
    float ay2 = fminf(fmaxf(sy + bh, 0.f), imgH);
    float aw = ax2 - ax1, ah = ay2 - ay1;
    float cx = ax1 + 0.5f * aw, cy = ay1 + 0.5f * ah;
    const float* rel = regb + (size_t)img * IMG_REG + c_regOff[lvl] + (size_t)aidx * 4;
    float dx = rel[0], dy = rel[1];
    float dw = fminf(rel[2], 4.135166556742356f);
    float dh = fminf(rel[3], 4.135166556742356f);
    float pcx = dx * aw + cx, pcy = dy * ah + cy;
    float pwd = expf(dw) * aw, phd = expf(dh) * ah;
    float x1 = pcx - 0.5f * pwd, y1 = pcy - 0.5f * phd;
    float x2 = pcx + 0.5f * pwd, y2 = pcy + 0.5f * phd;
    cboxes[outP * 4 + 0] = fminf(fmaxf(x1, 0.f), imgW);
    cboxes[outP * 4 + 1] = fminf(fmaxf(y1, 0.f), imgH);
    cboxes[outP * 4 + 2] = fminf(fmaxf(x2, 0.f), imgW);
    cboxes[outP * 4 + 3] = fminf(fmaxf(y2, 0.f), imgH);
    cscores[outP] = score;
    clabels[outP] = lbl;
}

__global__ __launch_bounds__(512) void nms_k(const float* __restrict__ cboxes,
                                             const float* __restrict__ cscores,
                                             const int* __restrict__ clabels,
                                             const int* __restrict__ ph, const int* __restrict__ pw,
                                             float* __restrict__ out)
{
    int img = blockIdx.x, tid = threadIdx.x;
    __shared__ float sSc[512];
    __shared__ int   sPos[512];
    __shared__ float bx1[400], by1[400], bx2[400], by2[400], sAr[400];
    __shared__ int   sKeep[400], sLbl[400];
    float imgH = (float)ph[0], imgW = (float)pw[0];
    float offm = fmaxf(imgH, imgW) + 1.0f;

    sSc[tid] = (tid < 400) ? cscores[img * 400 + tid] : -3.0f;
    sPos[tid] = tid;
    __syncthreads();

    for (int k = 2; k <= 512; k <<= 1) {
        for (int jj = k >> 1; jj > 0; jj >>= 1) {
            int ixj = tid ^ jj;
            if (ixj > tid) {
                float s1 = sSc[tid], s2 = sSc[ixj];
                int p1 = sPos[tid], p2 = sPos[ixj];
                bool bef = (s1 > s2) || (s1 == s2 && p1 < p2);
                bool sw = ((tid & k) == 0) ? (!bef) : bef;
                if (sw) { sSc[tid] = s2; sSc[ixj] = s1; sPos[tid] = p2; sPos[ixj] = p1; }
            }
            __syncthreads();
        }
    }

    if (tid < 400) {
        int p = sPos[tid];
        int lbl = clabels[img * 400 + p];
        float ofs = (float)lbl * offm;
        float x1 = cboxes[(img * 400 + p) * 4 + 0] + ofs;
        float y1 = cboxes[(img * 400 + p) * 4 + 1] + ofs;
        float x2 = cboxes[(img * 400 + p) * 4 + 2] + ofs;
        float y2 = cboxes[(img * 400 + p) * 4 + 3] + ofs;
        bx1[tid] = x1; by1[tid] = y1; bx2[tid] = x2; by2[tid] = y2;
        sAr[tid] = (x2 - x1) * (y2 - y1);
        sLbl[tid] = lbl;
        sKeep[tid] = (sSc[tid] > 0.05f) ? 1 : 0;
    }
    __syncthreads();

    for (int i = 0; i < 400; ++i) {
        if (sKeep[i]) {
            for (int j2 = i + 1 + tid; j2 < 400; j2 += 512) {
                float ltx = fmaxf(bx1[i], bx1[j2]), lty = fmaxf(by1[i], by1[j2]);
                float rbx = fminf(bx2[i], bx2[j2]), rby = fminf(by2[i], by2[j2]);
                float ww = fmaxf(rbx - ltx, 0.f), hh = fmaxf(rby - lty, 0.f);
                float inter = ww * hh;
                float iou = inter / (((sAr[i] + sAr[j2]) - inter) + 1e-9f);
                if (iou > 0.5f) sKeep[j2] = 0;
            }
        }
        __syncthreads();
    }

    if (tid == 0) {
        int rank = 0;
        for (int i = 0; i < 400 && rank < 100; ++i) {
            if (sKeep[i]) {
                int p = sPos[i];
                for (int kk = 0; kk < 4; ++kk)
                    out[(img * 100 + rank) * 4 + kk] = cboxes[(img * 400 + p) * 4 + kk];
                out[1600 + img * 100 + rank] = sSc[i];
                out[2000 + img * 100 + rank] = (float)sLbl[i];
                ++rank;
            }
        }
        for (; rank < 100; ++rank) {
            for (int kk = 0; kk < 4; ++kk) out[(img * 100 + rank) * 4 + kk] = 0.f;
            out[1600 + img * 100 + rank] = 0.f;
            out[2000 + img * 100 + rank] = -1.0f;
        }
    }
}

// ---------------------------------------------------------------------------
extern "C" void kernel_launch(void* const* d_in, const int* in_sizes, int n_in,
                              void* d_out, int out_size, void* d_ws, size_t ws_size,
                              hipStream_t stream)
{
    const float* f0 = (const float*)d_in[0];
    const float* f1 = (const float*)d_in[1];
    const float* f2 = (const float*)d_in[2];
    const float* f3 = (const float*)d_in[3];
    const float* cls_tw = (const float*)d_in[4];
    const float* cls_tb = (const float*)d_in[5];
    const float* cls_ow = (const float*)d_in[6];
    const float* cls_ob = (const float*)d_in[7];
    const float* reg_tw = (const float*)d_in[8];
    const float* reg_tb = (const float*)d_in[9];
    const float* reg_ow = (const float*)d_in[10];
    const float* reg_ob = (const float*)d_in[11];
    const int* ph = (const int*)d_in[12];
    const int* pw = (const int*)d_in[13];
    float* out = (float*)d_out;

    char* ws = (char*)d_ws;
    size_t off = 0;
    auto alloc = [&](size_t bytes) -> void* {
        void* p = ws + off;
        off = (off + bytes + 255) & ~(size_t)255;
        return p;
    };
    // bufA is aliased with keys: tower ping slab (44.6MB) lives inside keys (62.7MB);
    // keys only written by the out-conv, after bufA's last read (layer 3 input).
    float*    bufA   = (float*)alloc((size_t)4 * IMG_KEY * 4);                 // 62.7 MB
    unsigned* keys   = (unsigned*)bufA;
    float*    bufB   = (float*)alloc((size_t)2 * 4 * 256 * CONCAT_PX * 4);     // 44.6 MB
    float*    regb   = (float*)alloc((size_t)4 * IMG_REG * 4);
    unsigned* hist   = (unsigned*)alloc((size_t)16 * HBINS * 4);
    unsigned* cnt    = (unsigned*)alloc(16 * 4);
    unsigned* tbin   = (unsigned*)alloc(16 * 4);
    uint2*    comp   = (uint2*)alloc((size_t)16 * CAP * 8);
    unsigned long long* part = (unsigned long long*)alloc((size_t)16 * 16 * 100 * 8);
    uint2*    topk   = (uint2*)alloc((size_t)1600 * 8);
    float*    cboxes = (float*)alloc((size_t)4 * 400 * 4 * 4);
    float*    cscores= (float*)alloc((size_t)4 * 400 * 4);
    int*      clabels= (int*)alloc((size_t)4 * 400 * 4);

    hipMemsetAsync(hist, 0, (size_t)16 * HBINS * 4, stream);
    hipMemsetAsync(cnt, 0, 64, stream);

    const size_t LW = (size_t)256 * 256 * 9;
    // tower: L0 f->A, L1 A->B, L2 B->A, L3 A->B
    float* seqIn[4]  = {nullptr, bufA, bufB, bufA};
    float* seqOut[4] = {bufA, bufB, bufA, bufB};
    for (int layer = 0; layer < 4; ++layer) {
        conv_fused<<<dim3(43, 4, 8), 256, 0, stream>>>(
            f0, f1, f2, f3, seqIn[layer], seqOut[layer],
            cls_tw + LW * layer, cls_tb + 256 * layer,
            reg_tw + LW * layer, reg_tb + 256 * layer,
            nullptr, nullptr, layer, 0);
    }
    // fused out-convs: reads bufB, writes keys(=bufA) + regb
    conv_fused<<<dim3(43, 13, 4), 256, 0, stream>>>(
        f0, f1, f2, f3, bufB, nullptr,
        cls_ow, cls_ob, reg_ow, reg_ob,
        keys, regb, 4, 1);

    hist_k<<<dim3(180, 16), 256, 0, stream>>>(keys, hist);
    thresh_k<<<16, 256, 0, stream>>>(hist, tbin);
    compact_k<<<dim3(180, 16), 256, 0, stream>>>(keys, tbin, cnt, comp);
    partial_topk<<<dim3(16, 16), 256, 0, stream>>>(cnt, comp, part);
    merge_topk<<<16, 256, 0, stream>>>(part, topk);
    decode_k<<<16, 128, 0, stream>>>(topk, regb, cboxes, cscores, clabels, ph, pw);
    nms_k<<<4, 512, 0, stream>>>(cboxes, cscores, clabels, ph, pw, out);
}

// Round 3
// 5357.289 us; speedup vs baseline: 3.4212x; 1.2838x over previous
//
#include <hip/hip_runtime.h>
#include <math.h>

#define A_NUM 9
#define NCLS 80
#define IMG_KEY 3916800   // 720*5440
#define IMG_REG 195840    // 36*5440
#define CAP 8192
#define HBINS 16384
#define CONCAT_PX 5440

__constant__ int   c_W[4]       = {64, 32, 16, 8};
__constant__ int   c_stride[4]  = {8, 16, 32, 64};
__constant__ float c_sizes[4][3]= {{32.f,40.f,50.f},{64.f,80.f,101.f},{128.f,161.f,203.f},{256.f,322.f,406.f}};
__constant__ int   c_keyOff[4]  = {0, 2949120, 3686400, 3870720};
__constant__ int   c_keyCnt[4]  = {2949120, 737280, 184320, 46080};
__constant__ int   c_regOff[4]  = {0, 147456, 184320, 193536};
__constant__ int   c_lvlPx[4]   = {0, 4096, 5120, 5376};

// ---------------------------------------------------------------------------
// Fused 3x3 SAME conv, fp32, all 4 levels in one dispatch (43 tiles of 8x16).
// Thread tile: 4co x (2x4)px. Weight LDS: [co][ci*12+k], co-stride 100
// (4co-groups spread 2-way over banks = free; 16B-aligned b128 reads).
// Register-prefetch pipeline: next ci-chunk's global loads issued right after
// barrier, consumed by next iteration's ds_writes (latency hidden by compute).
// ---------------------------------------------------------------------------
__global__ __launch_bounds__(256, 3) void conv_fused(
    const float* __restrict__ f0, const float* __restrict__ f1,
    const float* __restrict__ f2, const float* __restrict__ f3,
    const float* __restrict__ bufIn, float* __restrict__ bufOut,
    const float* __restrict__ wA, const float* __restrict__ bA,
    const float* __restrict__ wB, const float* __restrict__ bB,
    unsigned* __restrict__ keys, float* __restrict__ regb,
    int layer, int mode)
{
    const int tid = threadIdx.x;
    int t43 = blockIdx.x;
    int lvl, ty, tx;
    if (t43 < 32)      { lvl = 0; ty = t43 >> 2; tx = t43 & 3; }
    else if (t43 < 40) { int u = t43 - 32; lvl = 1; ty = u >> 1; tx = u & 1; }
    else if (t43 < 42) { lvl = 2; ty = t43 - 40; tx = 0; }
    else               { lvl = 3; ty = 0; tx = 0; }
    const int W = 64 >> lvl, H = W, HW = W * W;
    const int tileY = ty * 8, tileX = tx * 16;

    int img, head, coBase, C_out, epi;
    const float *wsel, *bsel;
    if (mode == 0) {
        img = blockIdx.z & 3; head = blockIdx.z >> 2;
        coBase = blockIdx.y * 64; C_out = 256; epi = 0;
        wsel = head ? wB : wA; bsel = head ? bB : bA;
    } else {
        img = blockIdx.z;
        if (blockIdx.y < 12) { head = 0; coBase = blockIdx.y * 64; C_out = 720; epi = 1; wsel = wA; bsel = bA; }
        else                 { head = 1; coBase = 0;               C_out = 36;  epi = 2; wsel = wB; bsel = bB; }
    }

    const float* srcBase; int chStride;
    if (mode == 0 && layer == 0) {
        const float* f = (lvl == 0) ? f0 : ((lvl == 1) ? f1 : ((lvl == 2) ? f2 : f3));
        srcBase = f + (size_t)img * 256 * HW; chStride = HW;
    } else {
        srcBase = bufIn + ((size_t)(head * 4 + img) * 256) * CONCAT_PX + c_lvlPx[lvl];
        chStride = CONCAT_PX;
    }
    const float* wBase = wsel + (size_t)coBase * 2304;

    const int cog4 = (tid >> 4) * 4;
    const int pg   = tid & 15;
    const int py0  = (pg >> 2) * 2;
    const int px0  = (pg & 3) * 4;

    __shared__ float sIn[1600];   // 8ci x 10 rows x 20 cols (18 valid + pad)
    __shared__ float sW[6400];    // [coL*100 + ci*12 + k]

    // precomputed staging tables
    int inOff[7];
    #pragma unroll
    for (int e = 0; e < 7; ++e) {
        int t = tid + e * 256;
        int off = -1;
        if (t < 1600) {
            int ci = t / 200, rem = t - ci * 200;
            int iy = rem / 20, ix = rem - iy * 20;
            int gy = tileY + iy - 1, gx = tileX + ix - 1;
            if (ix < 18 && (unsigned)gy < (unsigned)H && (unsigned)gx < (unsigned)W)
                off = ci * chStride + gy * W + gx;
        }
        inOff[e] = off;
    }
    unsigned wPack[18];   // (gOff<<13) | ldsOff ; bit31 = invalid(co>=C_out)
    #pragma unroll
    for (int e = 0; e < 18; ++e) {
        int t = tid + e * 256;                 // t < 4608
        int coL = t / 72, rem = t - coL * 72;
        int ciL = rem / 9, kk = rem - ciL * 9;
        unsigned lds = (unsigned)(coL * 100 + ciL * 12 + kk);
        unsigned g   = (unsigned)(coL * 2304 + ciL * 9 + kk);
        wPack[e] = (coBase + coL < C_out) ? ((g << 13) | lds) : (0x80000000u | lds);
    }

    float rIn[7], rW[18];
    auto loadIn = [&](int cc) {
        const float* isrc = srcBase + cc * chStride;
        #pragma unroll
        for (int e = 0; e < 7; ++e)
            rIn[e] = (inOff[e] >= 0) ? isrc[inOff[e]] : 0.f;
    };
    auto loadW = [&](int cc) {
        const float* wsrc = wBase + cc * 9;
        #pragma unroll
        for (int e = 0; e < 18; ++e) {
            unsigned p = wPack[e];
            rW[e] = (p & 0x80000000u) ? 0.f : wsrc[p >> 13];
        }
    };

    float acc[4][8] = {};
    loadIn(0); loadW(0);

    for (int cc = 0; cc < 256; cc += 8) {
        #pragma unroll
        for (int e = 0; e < 7; ++e) {
            int t = tid + e * 256;
            if (t < 1600) sIn[t] = rIn[e];
        }
        #pragma unroll
        for (int e = 0; e < 18; ++e)
            sW[wPack[e] & 8191u] = rW[e];
        __syncthreads();
        if (cc + 8 < 256) { loadIn(cc + 8); loadW(cc + 8); }

        #pragma unroll
        for (int ci = 0; ci < 8; ++ci) {
            float xr[4][6];
            #pragma unroll
            for (int iy = 0; iy < 4; ++iy) {
                const float4 a = *reinterpret_cast<const float4*>(&sIn[ci * 200 + (py0 + iy) * 20 + px0]);
                const float2 b = *reinterpret_cast<const float2*>(&sIn[ci * 200 + (py0 + iy) * 20 + px0 + 4]);
                xr[iy][0] = a.x; xr[iy][1] = a.y; xr[iy][2] = a.z; xr[iy][3] = a.w;
                xr[iy][4] = b.x; xr[iy][5] = b.y;
            }
            #pragma unroll
            for (int r = 0; r < 4; ++r) {
                const int wb = (cog4 + r) * 100 + ci * 12;
                const float4 w0 = *reinterpret_cast<const float4*>(&sW[wb]);
                const float4 w1 = *reinterpret_cast<const float4*>(&sW[wb + 4]);
                const float  w8 = sW[wb + 8];
                float wr[9];
                wr[0] = w0.x; wr[1] = w0.y; wr[2] = w0.z; wr[3] = w0.w;
                wr[4] = w1.x; wr[5] = w1.y; wr[6] = w1.z; wr[7] = w1.w; wr[8] = w8;
                #pragma unroll
                for (int py = 0; py < 2; ++py)
                    #pragma unroll
                    for (int px = 0; px < 4; ++px) {
                        float s = acc[r][py * 4 + px];
                        #pragma unroll
                        for (int ky = 0; ky < 3; ++ky)
                            #pragma unroll
                            for (int kx = 0; kx < 3; ++kx)
                                s = fmaf(xr[py + ky][px + kx], wr[ky * 3 + kx], s);
                        acc[r][py * 4 + px] = s;
                    }
            }
        }
        __syncthreads();
    }

    if (px0 >= W) return;   // lvl3 right-half threads
    #pragma unroll
    for (int r = 0; r < 4; ++r) {
        int coG = coBase + cog4 + r;
        if (coG >= C_out) continue;
        float b = bsel[coG];
        for (int py = 0; py < 2; ++py) {
            int y = tileY + py0 + py;
            float v0 = acc[r][py * 4 + 0] + b;
            float v1 = acc[r][py * 4 + 1] + b;
            float v2 = acc[r][py * 4 + 2] + b;
            float v3 = acc[r][py * 4 + 3] + b;
            if (epi == 0) {
                v0 = fmaxf(v0, 0.f); v1 = fmaxf(v1, 0.f); v2 = fmaxf(v2, 0.f); v3 = fmaxf(v3, 0.f);
                float* o = bufOut + ((size_t)(head * 4 + img) * 256 + coG) * CONCAT_PX
                                  + c_lvlPx[lvl] + y * W + tileX + px0;
                *reinterpret_cast<float4*>(o) = make_float4(v0, v1, v2, v3);
            } else if (epi == 1) {
                float s0 = 1.0f / (1.0f + expf(-v0));
                float s1 = 1.0f / (1.0f + expf(-v1));
                float s2 = 1.0f / (1.0f + expf(-v2));
                float s3 = 1.0f / (1.0f + expf(-v3));
                unsigned k0 = (s0 > 0.05f) ? __float_as_uint(s0) : 0u;
                unsigned k1 = (s1 > 0.05f) ? __float_as_uint(s1) : 0u;
                unsigned k2 = (s2 > 0.05f) ? __float_as_uint(s2) : 0u;
                unsigned k3 = (s3 > 0.05f) ? __float_as_uint(s3) : 0u;
                unsigned* o = keys + (size_t)img * IMG_KEY + c_keyOff[lvl]
                                   + (size_t)coG * HW + y * W + tileX + px0;
                *reinterpret_cast<uint4*>(o) = make_uint4(k0, k1, k2, k3);
            } else {
                int a = coG >> 2, jj = coG & 3;
                int pBase = y * W + tileX + px0;
                #pragma unroll
                for (int px = 0; px < 4; ++px) {
                    float v = acc[r][py * 4 + px] + b;
                    regb[(size_t)img * IMG_REG + c_regOff[lvl] + (size_t)((pBase + px) * A_NUM + a) * 4 + jj] = v;
                }
            }
        }
    }
}

// ---------------------------------------------------------------------------
__global__ __launch_bounds__(256) void hist_k(const unsigned* __restrict__ keys,
                                              unsigned* __restrict__ hist)
{
    int il = blockIdx.y, img = il >> 2, lvl = il & 3;
    int n = c_keyCnt[lvl];
    int chunk = blockIdx.x * 16384;
    if (chunk >= n) return;
    __shared__ unsigned h[HBINS];   // 64 KB
    for (int t = threadIdx.x; t < HBINS; t += 256) h[t] = 0;
    __syncthreads();
    const uint4* k4 = (const uint4*)(keys + (size_t)img * IMG_KEY + c_keyOff[lvl]);
    int i0 = chunk >> 2, i1 = min(chunk + 16384, n) >> 2;
    for (int i = i0 + (int)threadIdx.x; i < i1; i += 256) {
        uint4 kv = k4[i];
        if (kv.x) atomicAdd(&h[kv.x >> 18], 1u);
        if (kv.y) atomicAdd(&h[kv.y >> 18], 1u);
        if (kv.z) atomicAdd(&h[kv.z >> 18], 1u);
        if (kv.w) atomicAdd(&h[kv.w >> 18], 1u);
    }
    __syncthreads();
    unsigned* gh = hist + (size_t)il * HBINS;
    for (int t = threadIdx.x; t < HBINS; t += 256)
        if (h[t]) atomicAdd(&gh[t], h[t]);
}

__global__ __launch_bounds__(256) void thresh_k(const unsigned* __restrict__ hist,
                                                unsigned* __restrict__ tbin)
{
    const unsigned* h = hist + (size_t)blockIdx.x * HBINS;
    __shared__ unsigned cs[256];
    int tid = threadIdx.x;
    unsigned s = 0;
    int base = tid * 64;
    for (int q = 0; q < 64; ++q) { int b = base + q; if (b >= 1) s += h[b]; }
    cs[tid] = s;
    __syncthreads();
    if (tid == 0) {
        unsigned total = 0, sel = 0;
        for (int c = 255; c >= 0; --c) {
            if (total + cs[c] >= 100u) {
                int lo = (c == 0) ? 1 : c * 64;
                for (int b = c * 64 + 63; b >= lo; --b) {
                    total += h[b];
                    if (total >= 100u) { sel = (unsigned)b; break; }
                }
                break;
            }
            total += cs[c];
        }
        tbin[blockIdx.x] = sel;
    }
}

// two-pass per-block aggregation: ONE global atomic per block
__global__ __launch_bounds__(256) void compact_k(const unsigned* __restrict__ keys,
                                                 const unsigned* __restrict__ tbin,
                                                 unsigned* __restrict__ cnt,
                                                 uint2* __restrict__ comp)
{
    int il = blockIdx.y, img = il >> 2, lvl = il & 3;
    int n = c_keyCnt[lvl];
    int chunk = blockIdx.x * 16384;
    if (chunk >= n) return;
    const unsigned* kbase = keys + (size_t)img * IMG_KEY + c_keyOff[lvl];
    const uint4* k4 = (const uint4*)kbase;
    unsigned thr = tbin[il] << 18;
    int shift = 12 - 2 * lvl;
    int hwm = (1 << shift) - 1;
    int i0 = chunk >> 2, i1 = min(chunk + 16384, n) >> 2;
    __shared__ unsigned lcnt, lbase, lcur;
    if (threadIdx.x == 0) { lcnt = 0; lcur = 0; }
    __syncthreads();
    unsigned myc = 0;
    for (int i = i0 + (int)threadIdx.x; i < i1; i += 256) {
        uint4 kv = k4[i];
        myc += (kv.x != 0u && kv.x >= thr);
        myc += (kv.y != 0u && kv.y >= thr);
        myc += (kv.z != 0u && kv.z >= thr);
        myc += (kv.w != 0u && kv.w >= thr);
    }
    if (myc) atomicAdd(&lcnt, myc);
    __syncthreads();
    if (threadIdx.x == 0 && lcnt) lbase = atomicAdd(&cnt[il], lcnt);
    __syncthreads();
    if (lcnt == 0) return;
    uint2* c = comp + (size_t)il * CAP;
    for (int i = i0 + (int)threadIdx.x; i < i1; i += 256) {
        uint4 kv = k4[i];
        unsigned kk[4] = {kv.x, kv.y, kv.z, kv.w};
        #pragma unroll
        for (int j = 0; j < 4; ++j) {
            unsigned key = kk[j];
            if (key != 0u && key >= thr) {
                int t = i * 4 + j;
                int co = t >> shift, p = t & hwm;
                int a = co / NCLS, cls = co - a * NCLS;
                unsigned idx = (unsigned)((p * A_NUM + a) * NCLS + cls);
                unsigned pos = lbase + atomicAdd(&lcur, 1u);
                if (pos < CAP) c[pos] = make_uint2(key, idx);
            }
        }
    }
}

// single-block bitonic sort of up to CAP candidates -> exact top-100
__global__ __launch_bounds__(256) void topsort_k(const unsigned* __restrict__ cnt,
                                                 const uint2* __restrict__ comp,
                                                 uint2* __restrict__ topk)
{
    __shared__ unsigned long long s[CAP];   // 64 KB
    int il = blockIdx.x, tid = threadIdx.x;
    int n = (int)min(cnt[il], (unsigned)CAP);
    const uint2* c = comp + (size_t)il * CAP;
    for (int i = tid; i < CAP; i += 256) {
        unsigned long long v = 0ull;
        if (i < n) {
            uint2 e = c[i];
            v = ((unsigned long long)e.x << 32) | (unsigned long long)(~e.y);
        }
        s[i] = v;
    }
    for (int k = 2; k <= CAP; k <<= 1) {
        for (int j = k >> 1; j > 0; j >>= 1) {
            __syncthreads();
            for (int p = tid; p < CAP / 2; p += 256) {
                int i = ((p & ~(j - 1)) << 1) | (p & (j - 1));
                int ixj = i | j;
                unsigned long long a = s[i], b = s[ixj];
                if (((i & k) == 0) ? (a < b) : (a > b)) { s[i] = b; s[ixj] = a; }
            }
        }
    }
    __syncthreads();
    if (tid < 100) {
        unsigned long long v = s[tid];
        topk[il * 100 + tid] = make_uint2((unsigned)(v >> 32), ~(unsigned)(v & 0xFFFFFFFFull));
    }
}

// ---------------------------------------------------------------------------
__global__ void decode_k(const uint2* __restrict__ topk, const float* __restrict__ regb,
                         float* __restrict__ cboxes, float* __restrict__ cscores,
                         int* __restrict__ clabels, const int* __restrict__ ph, const int* __restrict__ pw)
{
    int il = blockIdx.x, img = il >> 2, lvl = il & 3;
    int j = threadIdx.x;
    if (j >= 100) return;
    float imgW = (float)pw[0], imgH = (float)ph[0];
    uint2 tk = topk[il * 100 + j];
    int outP = img * 400 + lvl * 100 + j;
    if (tk.x == 0u) {
        cboxes[outP * 4 + 0] = 0.f; cboxes[outP * 4 + 1] = 0.f;
        cboxes[outP * 4 + 2] = 0.f; cboxes[outP * 4 + 3] = 0.f;
        cscores[outP] = -1.0f; clabels[outP] = -1;
        return;
    }
    float score = __uint_as_float(tk.x);
    unsigned idx = tk.y;
    int aidx = (int)(idx / NCLS);
    int lbl  = (int)(idx - (unsigned)aidx * NCLS);
    int a = aidx % A_NUM, p = aidx / A_NUM;
    int W = c_W[lvl];
    int y = p / W, x = p - y * W;
    int r = a / 3, si = a - r * 3;
    float ratio = (r == 0) ? 0.5f : ((r == 1) ? 1.0f : 2.0f);
    float size = c_sizes[lvl][si];
    float hr = sqrtf(ratio);
    float wr = 1.0f / hr;
    float wsz = wr * size, hsz = hr * size;
    float bw = rintf(wsz * 0.5f), bh = rintf(hsz * 0.5f);
    float sx = (float)(x * c_stride[lvl]), sy = (float)(y * c_stride[lvl]);
    float ax1 = fminf(fmaxf(sx - bw, 0.f), imgW);
    float ay1 = fminf(fmaxf(sy - bh, 0.f), imgH);
    float ax2 = fminf(fmaxf(sx + bw, 0.f), imgW);
    float ay2 = fminf(fmaxf(sy + bh, 0.f), imgH);
    float aw = ax2 - ax1, ah = ay2 - ay1;
    float cx = ax1 + 0.5f * aw, cy = ay1 + 0.5f * ah;
    const float* rel = regb + (size_t)img * IMG_REG + c_regOff[lvl] + (size_t)aidx * 4;
    float dx = rel[0], dy = rel[1];
    float dw = fminf(rel[2], 4.135166556742356f);
    float dh = fminf(rel[3], 4.135166556742356f);
    float pcx = dx * aw + cx, pcy = dy * ah + cy;
    float pwd = expf(dw) * aw, phd = expf(dh) * ah;
    float x1 = pcx - 0.5f * pwd, y1 = pcy - 0.5f * phd;
    float x2 = pcx + 0.5f * pwd, y2 = pcy + 0.5f * phd;
    cboxes[outP * 4 + 0] = fminf(fmaxf(x1, 0.f), imgW);
    cboxes[outP * 4 + 1] = fminf(fmaxf(y1, 0.f), imgH);
    cboxes[outP * 4 + 2] = fminf(fmaxf(x2, 0.f), imgW);
    cboxes[outP * 4 + 3] = fminf(fmaxf(y2, 0.f), imgH);
    cscores[outP] = score;
    clabels[outP] = lbl;
}

__global__ __launch_bounds__(512) void nms_k(const float* __restrict__ cboxes,
                                             const float* __restrict__ cscores,
                                             const int* __restrict__ clabels,
                                             const int* __restrict__ ph, const int* __restrict__ pw,
                                             float* __restrict__ out)
{
    int img = blockIdx.x, tid = threadIdx.x;
    __shared__ float sSc[512];
    __shared__ int   sPos[512];
    __shared__ float bx1[400], by1[400], bx2[400], by2[400], sAr[400];
    __shared__ int   sKeep[400], sLbl[400];
    float imgH = (float)ph[0], imgW = (float)pw[0];
    float offm = fmaxf(imgH, imgW) + 1.0f;

    sSc[tid] = (tid < 400) ? cscores[img * 400 + tid] : -3.0f;
    sPos[tid] = tid;
    __syncthreads();

    for (int k = 2; k <= 512; k <<= 1) {
        for (int jj = k >> 1; jj > 0; jj >>= 1) {
            int ixj = tid ^ jj;
            if (ixj > tid) {
                float s1 = sSc[tid], s2 = sSc[ixj];
                int p1 = sPos[tid], p2 = sPos[ixj];
                bool bef = (s1 > s2) || (s1 == s2 && p1 < p2);
                bool sw = ((tid & k) == 0) ? (!bef) : bef;
                if (sw) { sSc[tid] = s2; sSc[ixj] = s1; sPos[tid] = p2; sPos[ixj] = p1; }
            }
            __syncthreads();
        }
    }

    if (tid < 400) {
        int p = sPos[tid];
        int lbl = clabels[img * 400 + p];
        float ofs = (float)lbl * offm;
        float x1 = cboxes[(img * 400 + p) * 4 + 0] + ofs;
        float y1 = cboxes[(img * 400 + p) * 4 + 1] + ofs;
        float x2 = cboxes[(img * 400 + p) * 4 + 2] + ofs;
        float y2 = cboxes[(img * 400 + p) * 4 + 3] + ofs;
        bx1[tid] = x1; by1[tid] = y1; bx2[tid] = x2; by2[tid] = y2;
        sAr[tid] = (x2 - x1) * (y2 - y1);
        sLbl[tid] = lbl;
        sKeep[tid] = (sSc[tid] > 0.05f) ? 1 : 0;
    }
    __syncthreads();

    for (int i = 0; i < 400; ++i) {
        if (sKeep[i]) {
            for (int j2 = i + 1 + tid; j2 < 400; j2 += 512) {
                float ltx = fmaxf(bx1[i], bx1[j2]), lty = fmaxf(by1[i], by1[j2]);
                float rbx = fminf(bx2[i], bx2[j2]), rby = fminf(by2[i], by2[j2]);
                float ww = fmaxf(rbx - ltx, 0.f), hh = fmaxf(rby - lty, 0.f);
                float inter = ww * hh;
                float iou = inter / (((sAr[i] + sAr[j2]) - inter) + 1e-9f);
                if (iou > 0.5f) sKeep[j2] = 0;
            }
        }
        __syncthreads();
    }

    if (tid == 0) {
        int rank = 0;
        for (int i = 0; i < 400 && rank < 100; ++i) {
            if (sKeep[i]) {
                int p = sPos[i];
                for (int kk = 0; kk < 4; ++kk)
                    out[(img * 100 + rank) * 4 + kk] = cboxes[(img * 400 + p) * 4 + kk];
                out[1600 + img * 100 + rank] = sSc[i];
                out[2000 + img * 100 + rank] = (float)sLbl[i];
                ++rank;
            }
        }
        for (; rank < 100; ++rank) {
            for (int kk = 0; kk < 4; ++kk) out[(img * 100 + rank) * 4 + kk] = 0.f;
            out[1600 + img * 100 + rank] = 0.f;
            out[2000 + img * 100 + rank] = -1.0f;
        }
    }
}

// ---------------------------------------------------------------------------
extern "C" void kernel_launch(void* const* d_in, const int* in_sizes, int n_in,
                              void* d_out, int out_size, void* d_ws, size_t ws_size,
                              hipStream_t stream)
{
    const float* f0 = (const float*)d_in[0];
    const float* f1 = (const float*)d_in[1];
    const float* f2 = (const float*)d_in[2];
    const float* f3 = (const float*)d_in[3];
    const float* cls_tw = (const float*)d_in[4];
    const float* cls_tb = (const float*)d_in[5];
    const float* cls_ow = (const float*)d_in[6];
    const float* cls_ob = (const float*)d_in[7];
    const float* reg_tw = (const float*)d_in[8];
    const float* reg_tb = (const float*)d_in[9];
    const float* reg_ow = (const float*)d_in[10];
    const float* reg_ob = (const float*)d_in[11];
    const int* ph = (const int*)d_in[12];
    const int* pw = (const int*)d_in[13];
    float* out = (float*)d_out;

    char* ws = (char*)d_ws;
    size_t off = 0;
    auto alloc = [&](size_t bytes) -> void* {
        void* p = ws + off;
        off = (off + bytes + 255) & ~(size_t)255;
        return p;
    };
    // bufA aliased with keys (tower ping slab fits inside keys; keys written
    // only by the out-conv, after bufA's last read).
    float*    bufA   = (float*)alloc((size_t)4 * IMG_KEY * 4);                 // 62.7 MB
    unsigned* keys   = (unsigned*)bufA;
    float*    bufB   = (float*)alloc((size_t)2 * 4 * 256 * CONCAT_PX * 4);     // 44.6 MB
    float*    regb   = (float*)alloc((size_t)4 * IMG_REG * 4);
    unsigned* hist   = (unsigned*)alloc((size_t)16 * HBINS * 4);               // 1 MB
    unsigned* cnt    = (unsigned*)alloc(16 * 4);
    unsigned* tbin   = (unsigned*)alloc(16 * 4);
    uint2*    comp   = (uint2*)alloc((size_t)16 * CAP * 8);                    // 1 MB
    uint2*    topk   = (uint2*)alloc((size_t)1600 * 8);
    float*    cboxes = (float*)alloc((size_t)4 * 400 * 4 * 4);
    float*    cscores= (float*)alloc((size_t)4 * 400 * 4);
    int*      clabels= (int*)alloc((size_t)4 * 400 * 4);

    hipMemsetAsync(hist, 0, (size_t)16 * HBINS * 4, stream);
    hipMemsetAsync(cnt, 0, 64, stream);

    const size_t LW = (size_t)256 * 256 * 9;
    // tower: L0 f->A, L1 A->B, L2 B->A, L3 A->B
    float* seqIn[4]  = {nullptr, bufA, bufB, bufA};
    float* seqOut[4] = {bufA, bufB, bufA, bufB};
    for (int layer = 0; layer < 4; ++layer) {
        conv_fused<<<dim3(43, 4, 8), 256, 0, stream>>>(
            f0, f1, f2, f3, seqIn[layer], seqOut[layer],
            cls_tw + LW * layer, cls_tb + 256 * layer,
            reg_tw + LW * layer, reg_tb + 256 * layer,
            nullptr, nullptr, layer, 0);
    }
    // fused out-convs: reads bufB, writes keys(=bufA) + regb
    conv_fused<<<dim3(43, 13, 4), 256, 0, stream>>>(
        f0, f1, f2, f3, bufB, nullptr,
        cls_ow, cls_ob, reg_ow, reg_ob,
        keys, regb, 4, 1);

    hist_k<<<dim3(180, 16), 256, 0, stream>>>(keys, hist);
    thresh_k<<<16, 256, 0, stream>>>(hist, tbin);
    compact_k<<<dim3(180, 16), 256, 0, stream>>>(keys, tbin, cnt, comp);
    topsort_k<<<16, 256, 0, stream>>>(cnt, comp, topk);
    decode_k<<<16, 128, 0, stream>>>(topk, regb, cboxes, cscores, clabels, ph, pw);
    nms_k<<<4, 512, 0, stream>>>(cboxes, cscores, clabels, ph, pw, out);
}